// Round 1
// baseline (150.014 us; speedup 1.0000x reference)
//
#include <hip/hip_runtime.h>
#include <hip/hip_bf16.h>

// Linear layer: out[M,N] = x[M,K] @ W[N,K]^T + b[N], fp32 in/out.
// M=32768, N=512, K=512. Strategy: cast to bf16 in-register during LDS
// staging, MFMA 16x16x32 bf16 accumulate fp32. Memory-bound (~129 MB HBM).

#define M_DIM 32768
#define N_DIM 512
#define K_DIM 512
#define BM 128
#define BN 128
#define BK 32
#define LDA 40   // padded LDS row stride (bf16 elems): breaks 64B-stride bank pattern

typedef __bf16 bf16x8 __attribute__((ext_vector_type(8)));
typedef __bf16 bf16x4 __attribute__((ext_vector_type(4)));
typedef float floatx4 __attribute__((ext_vector_type(4)));

__global__ __launch_bounds__(256) void linear_bf16_mfma(
    const float* __restrict__ A,    // [M, K] input
    const float* __restrict__ W,    // [N, K] weight (row-major [out, in])
    const float* __restrict__ bias, // [N]
    float* __restrict__ C)          // [M, N]
{
    __shared__ __bf16 sA[BM * LDA];
    __shared__ __bf16 sW[BN * LDA];

    const int t = threadIdx.x;
    const int mBlock = blockIdx.y * BM;
    const int nBlock = blockIdx.x * BN;

    const int wave = t >> 6;
    const int lane = t & 63;
    const int mW = (wave >> 1) * 64;   // wave's m-offset within tile
    const int nW = (wave & 1) * 64;    // wave's n-offset within tile
    const int kh = lane >> 4;          // 0..3: which 8-elem K-chunk
    const int l16 = lane & 15;

    floatx4 acc[4][4];
#pragma unroll
    for (int i = 0; i < 4; ++i)
#pragma unroll
        for (int j = 0; j < 4; ++j)
            acc[i][j] = (floatx4)0.f;

    // Staging: tile is 128 rows x 32 cols fp32 = 1024 float4; 256 threads x 4.
    // Thread t: rows t/8 + {0,32,64,96}, col = (t%8)*4. Coalesced 128B/row-segment.
    const int sRow = t >> 3;          // 0..31
    const int sCol = (t & 7) * 4;     // 0,4,...,28
    const float* aBase = A + (size_t)(mBlock + sRow) * K_DIM + sCol;
    const float* wBase = W + (size_t)(nBlock + sRow) * K_DIM + sCol;

    for (int kt = 0; kt < K_DIM; kt += BK) {
        __syncthreads();  // previous iteration's LDS reads done
#pragma unroll
        for (int i = 0; i < 4; ++i) {
            const int row = sRow + i * 32;
            floatx4 av = *(const floatx4*)(aBase + kt + (size_t)i * 32 * K_DIM);
            floatx4 wv = *(const floatx4*)(wBase + kt + (size_t)i * 32 * K_DIM);
            bf16x4 ab, wb;
#pragma unroll
            for (int j = 0; j < 4; ++j) {
                ab[j] = (__bf16)av[j];
                wb[j] = (__bf16)wv[j];
            }
            *(bf16x4*)&sA[row * LDA + sCol] = ab;
            *(bf16x4*)&sW[row * LDA + sCol] = wb;
        }
        __syncthreads();  // staging visible to all waves

        bf16x8 aF[4], wF[4];
#pragma unroll
        for (int mi = 0; mi < 4; ++mi)
            aF[mi] = *(const bf16x8*)&sA[(mW + mi * 16 + l16) * LDA + kh * 8];
#pragma unroll
        for (int ni = 0; ni < 4; ++ni)
            wF[ni] = *(const bf16x8*)&sW[(nW + ni * 16 + l16) * LDA + kh * 8];

#pragma unroll
        for (int mi = 0; mi < 4; ++mi)
#pragma unroll
            for (int ni = 0; ni < 4; ++ni)
                acc[mi][ni] = __builtin_amdgcn_mfma_f32_16x16x32_bf16(
                    aF[mi], wF[ni], acc[mi][ni], 0, 0, 0);
    }

    // Epilogue: D mapping col = lane&15, row = (lane>>4)*4 + reg (verified m89/m91).
#pragma unroll
    for (int ni = 0; ni < 4; ++ni) {
        const int gcol = nBlock + nW + ni * 16 + l16;
        const float bv = bias[gcol];
#pragma unroll
        for (int mi = 0; mi < 4; ++mi) {
            const int rowBase = mBlock + mW + mi * 16 + kh * 4;
#pragma unroll
            for (int r = 0; r < 4; ++r)
                C[(size_t)(rowBase + r) * N_DIM + gcol] = acc[mi][ni][r] + bv;
        }
    }
}

extern "C" void kernel_launch(void* const* d_in, const int* in_sizes, int n_in,
                              void* d_out, int out_size, void* d_ws, size_t ws_size,
                              hipStream_t stream) {
    const float* x = (const float*)d_in[0];    // [32768, 512]
    const float* w = (const float*)d_in[1];    // [512, 512]
    const float* b = (const float*)d_in[2];    // [512]
    float* out = (float*)d_out;                // [32768, 512]

    dim3 grid(N_DIM / BN, M_DIM / BM);  // (4, 256): N-tiles fastest -> A-tile L2 reuse
    dim3 block(256);
    linear_bf16_mfma<<<grid, block, 0, stream>>>(x, w, b, out);
}

// Round 2
// 141.974 us; speedup vs baseline: 1.0566x; 1.0566x over previous
//
#include <hip/hip_runtime.h>
#include <hip/hip_bf16.h>

// Linear layer: out[M,N] = x[M,K] @ W[N,K]^T + b[N], fp32 in/out.
// M=32768, N=512, K=512. bf16 MFMA, fp32 accumulate. Memory-bound.
// R2: XCD swizzle (A-tile sharers on same XCD L2), register-prefetch
// pipeline (global loads in flight during MFMA), nontemporal C stores.

#define M_DIM 32768
#define N_DIM 512
#define K_DIM 512
#define BM 128
#define BN 128
#define BK 32
#define LDA 40   // padded LDS row stride (bf16 elems)

typedef __bf16 bf16x8 __attribute__((ext_vector_type(8)));
typedef __bf16 bf16x4 __attribute__((ext_vector_type(4)));
typedef float floatx4 __attribute__((ext_vector_type(4)));

__global__ __launch_bounds__(256) void linear_bf16_mfma(
    const float* __restrict__ A,    // [M, K]
    const float* __restrict__ W,    // [N, K]
    const float* __restrict__ bias, // [N]
    float* __restrict__ C)          // [M, N]
{
    __shared__ __bf16 sA[BM * LDA];
    __shared__ __bf16 sW[BN * LDA];

    const int t = threadIdx.x;
    // XCD swizzle: the 4 n-tiles sharing one A-tile get bids {c, c+8, c+16, c+24}
    // (all == c mod 8 -> same XCD, adjacent dispatch slots on that XCD).
    const int bid = blockIdx.x;
    const int nT = (bid >> 3) & 3;
    const int mT = (bid & 7) | ((bid >> 5) << 3);
    const int mBlock = mT * BM;
    const int nBlock = nT * BN;

    const int wave = t >> 6;
    const int lane = t & 63;
    const int mW = (wave >> 1) * 64;
    const int nW = (wave & 1) * 64;
    const int kh = lane >> 4;
    const int l16 = lane & 15;

    floatx4 acc[4][4];
#pragma unroll
    for (int i = 0; i < 4; ++i)
#pragma unroll
        for (int j = 0; j < 4; ++j)
            acc[i][j] = (floatx4)0.f;

    // Staging: 128x32 fp32 tile = 1024 float4; thread t covers rows t/8+{0,32,64,96},
    // col (t%8)*4. Coalesced.
    const int sRow = t >> 3;
    const int sCol = (t & 7) * 4;
    const float* aBase = A + (size_t)(mBlock + sRow) * K_DIM + sCol;
    const float* wBase = W + (size_t)(nBlock + sRow) * K_DIM + sCol;

    // Prologue: prefetch tile kt=0 into registers.
    floatx4 pa[4], pw[4];
#pragma unroll
    for (int i = 0; i < 4; ++i) {
        pa[i] = *(const floatx4*)(aBase + (size_t)i * 32 * K_DIM);
        pw[i] = *(const floatx4*)(wBase + (size_t)i * 32 * K_DIM);
    }

    for (int kt = 0; kt < K_DIM; kt += BK) {
        // Convert prefetched fp32 -> bf16, store to LDS.
#pragma unroll
        for (int i = 0; i < 4; ++i) {
            const int row = sRow + i * 32;
            bf16x4 ab, wb;
#pragma unroll
            for (int j = 0; j < 4; ++j) {
                ab[j] = (__bf16)pa[i][j];
                wb[j] = (__bf16)pw[i][j];
            }
            *(bf16x4*)&sA[row * LDA + sCol] = ab;
            *(bf16x4*)&sW[row * LDA + sCol] = wb;
        }
        __syncthreads();  // staging visible

        // Issue next tile's global loads NOW — they fly during frag reads + MFMA
        // and drain at the end-of-body barrier.
        if (kt + BK < K_DIM) {
#pragma unroll
            for (int i = 0; i < 4; ++i) {
                pa[i] = *(const floatx4*)(aBase + kt + BK + (size_t)i * 32 * K_DIM);
                pw[i] = *(const floatx4*)(wBase + kt + BK + (size_t)i * 32 * K_DIM);
            }
        }

        bf16x8 aF[4], wF[4];
#pragma unroll
        for (int mi = 0; mi < 4; ++mi)
            aF[mi] = *(const bf16x8*)&sA[(mW + mi * 16 + l16) * LDA + kh * 8];
#pragma unroll
        for (int ni = 0; ni < 4; ++ni)
            wF[ni] = *(const bf16x8*)&sW[(nW + ni * 16 + l16) * LDA + kh * 8];

#pragma unroll
        for (int mi = 0; mi < 4; ++mi)
#pragma unroll
            for (int ni = 0; ni < 4; ++ni)
                acc[mi][ni] = __builtin_amdgcn_mfma_f32_16x16x32_bf16(
                    aF[mi], wF[ni], acc[mi][ni], 0, 0, 0);

        __syncthreads();  // all frag reads done before next iter's LDS writes
    }

    // Epilogue: D mapping col = lane&15, row = (lane>>4)*4 + reg.
    // Nontemporal: C is streaming write-only; keep it out of L2.
#pragma unroll
    for (int ni = 0; ni < 4; ++ni) {
        const int gcol = nBlock + nW + ni * 16 + l16;
        const float bv = bias[gcol];
#pragma unroll
        for (int mi = 0; mi < 4; ++mi) {
            const int rowBase = mBlock + mW + mi * 16 + kh * 4;
#pragma unroll
            for (int r = 0; r < 4; ++r)
                __builtin_nontemporal_store(acc[mi][ni][r] + bv,
                                            &C[(size_t)(rowBase + r) * N_DIM + gcol]);
        }
    }
}

extern "C" void kernel_launch(void* const* d_in, const int* in_sizes, int n_in,
                              void* d_out, int out_size, void* d_ws, size_t ws_size,
                              hipStream_t stream) {
    const float* x = (const float*)d_in[0];
    const float* w = (const float*)d_in[1];
    const float* b = (const float*)d_in[2];
    float* out = (float*)d_out;

    dim3 grid((M_DIM / BM) * (N_DIM / BN));  // 1024, 1D for XCD swizzle
    dim3 block(256);
    linear_bf16_mfma<<<grid, block, 0, stream>>>(x, w, b, out);
}